// Round 14
// baseline (356.711 us; speedup 1.0000x reference)
//
#include <hip/hip_runtime.h>
#include <hip/hip_bf16.h>

// GATv2 x2 + GlobalAttentionPooling for batched graphs.
// N=50000 nodes, E=500000 edges, G=50 graphs (1000 nodes each, edges in-graph).
// Layer1: IN=128 -> H=4 x D=64 (head-max -> 64). Layer2: 64 -> 4 x 128 (head-max -> 128).
// Pool: softmax(gate) per graph, weighted sum -> [50,128].
//
// R1: pooling atomics -> block-per-graph LDS. 1127->570us.
// R2: gat bf16 + XCD-contiguous swizzle (FETCH 444->54MB). ->488us.
// R3: fp32-VALU GEMMs -> bf16 MFMA (LDS-staged). ->422us.
// R4-R8: no-max softmax + packed f32x2 kept; strided grid-slots BAD (R7 L2
//   thrash), same-wave unroll BAD, shfl-bcast BAD.
// R9: 1-deep load pipeline + scalar cp[e] + epilogue gate: gat128 88->69. ->377us.
// R10: FAILED 2-wave edge split. R11: depth-2 pipeline. ->370us.
// R12: FAILED LDS-free GEMM, but exposed 2.7x C-store write amplification.
// R13: coalesced LDS-transpose epilogue (WRITE 140->~52MB). ->339us.
// R14: gat block-churn: 12504 blocks x 4 nodes each -> 3128 blocks x 16
//   CONSECUTIVE nodes (same-graph locality, unlike R7's strided version),
//   attn hoisted across nodes. scan_bsum folded into scan_add (-1 dispatch).
//   x pre-cast to bf16 in prep -> gemm1 A-fetch halved.

#define NN 50000
#define EE 500000
#define GG 50
#define NPG 1000
#define HH 4
#define NB_E ((EE + 255) / 256)        // 1954 edge-count blocks
#define NB_W 512                       // weight prep blocks
#define NB_X ((NN * 128) / (256 * 4))  // 6250 x-cast blocks (float4 each)

typedef unsigned short ushort_t;
typedef unsigned int uint_t;
typedef __attribute__((ext_vector_type(8))) short bf16x8;
typedef __attribute__((ext_vector_type(4))) float f32x4;
typedef __attribute__((ext_vector_type(2))) float f32x2;

__device__ __forceinline__ ushort_t bf16r(float f) {
  __hip_bfloat16 h = __float2bfloat16(f);
  return *reinterpret_cast<ushort_t*>(&h);
}

__device__ __forceinline__ f32x2 up2v(uint_t u) {
  f32x2 r;
  r.x = __uint_as_float(u << 16);
  r.y = __uint_as_float(u & 0xffff0000u);
  return r;
}

// ---------------- fused weight-prep + edge count + x cast ----------------

__global__ void prep_count(const int* __restrict__ dst, int* __restrict__ counts,
                           const float* __restrict__ Wl1, const float* __restrict__ Wr1,
                           const float* __restrict__ Wl2, const float* __restrict__ Wr2,
                           ushort_t* __restrict__ BW1, ushort_t* __restrict__ BW2,
                           const float* __restrict__ x, ushort_t* __restrict__ xb) {
  const int b = blockIdx.x;
  if (b < NB_E) {
    int i = b * 256 + threadIdx.x;
    if (i < EE) atomicAdd(&counts[dst[i]], 1);
  } else if (b < NB_E + NB_W) {
    int i = (b - NB_E) * 256 + threadIdx.x;   // 0..131071
    if (i < 512 * 128) {                      // BW1: [n<512][k<128], W1 [128][256]
      int n = i >> 7, k = i & 127;
      const float* W = (n < 256) ? Wl1 : Wr1;
      BW1[i] = bf16r(W[(size_t)k * 256 + (n & 255)]);
    } else {                                  // BW2: [n<1024][k<64], W2 [64][512]
      int j = i - 512 * 128;
      int n = j >> 6, k = j & 63;
      const float* W = (n < 512) ? Wl2 : Wr2;
      BW2[j] = bf16r(W[(size_t)k * 512 + (n & 511)]);
    }
  } else {
    // x -> bf16, 4 floats per thread
    size_t i = (size_t)(b - NB_E - NB_W) * 256 + threadIdx.x;
    float4 v = *(const float4*)(x + i * 4);
    uint2 pk;
    pk.x = (uint_t)bf16r(v.x) | ((uint_t)bf16r(v.y) << 16);
    pk.y = (uint_t)bf16r(v.z) | ((uint_t)bf16r(v.w) << 16);
    *(uint2*)(xb + i * 4) = pk;
  }
}

// ---------------- CSR scan (2 kernels) ----------------

__global__ void scan_block(const int* __restrict__ in, int* __restrict__ out,
                           int* __restrict__ bsum, int n) {
  __shared__ int tmp[256];
  int t = threadIdx.x;
  int i = blockIdx.x * 256 + t;
  int v = (i < n) ? in[i] : 0;
  tmp[t] = v;
  __syncthreads();
  for (int off = 1; off < 256; off <<= 1) {
    int a = (t >= off) ? tmp[t - off] : 0;
    __syncthreads();
    tmp[t] += a;
    __syncthreads();
  }
  if (i < n) out[i] = tmp[t] - v;
  if (t == 255) bsum[blockIdx.x] = tmp[t];
}

// adds prefix of bsum[0..blockIdx.x) to out (computed in-block); zeros cursor.
__global__ void scan_add(const int* __restrict__ bsum, int* __restrict__ out,
                         int* __restrict__ cursor, int n) {
  __shared__ int sred[4];
  const int t = threadIdx.x;
  const int b = blockIdx.x;
  int v = (t < b) ? bsum[t] : 0;   // nb=196 <= 256, covered
  v += __shfl_xor(v, 1);  v += __shfl_xor(v, 2);  v += __shfl_xor(v, 4);
  v += __shfl_xor(v, 8);  v += __shfl_xor(v, 16); v += __shfl_xor(v, 32);
  if ((t & 63) == 0) sred[t >> 6] = v;
  __syncthreads();
  const int base = sred[0] + sred[1] + sred[2] + sred[3];
  int i = b * 256 + t;
  if (i < n) {
    out[i] += base;
    cursor[i] = 0;
  }
}

__global__ void scatter_edges(const int* __restrict__ src, const int* __restrict__ dst,
                              const int* __restrict__ rowstart, int* __restrict__ cursor,
                              int* __restrict__ csr_src) {
  int i = blockIdx.x * 256 + threadIdx.x;
  if (i < EE) {
    int d = dst[i];
    int p = atomicAdd(&cursor[d], 1);
    csr_src[rowstart[d] + p] = src[i];
  }
}

// ---------------- bf16 MFMA GEMM: C[m][n] = A[m][:] . BW[n][:] + bias ----------------
// K-loop: LDS-staged (coalesced), 128x128 tile, 4 waves x (2x8) 16x16x32 mfma.
// Epilogue: wave-private LDS transpose band -> coalesced uint4 stores (R13).

template<int KDIM>
__global__ __launch_bounds__(256)
void gemm_mfma(const ushort_t* __restrict__ Ab, const ushort_t* __restrict__ BW,
               const float* __restrict__ bl, const float* __restrict__ br, int nhalf,
               ushort_t* __restrict__ C, int nstride) {
  constexpr int RS  = 72;    // staging row stride (bf16)
  constexpr int EPS = 132;   // epilogue row stride (bf16); 4*32*132 <= 2*128*72
  __shared__ __align__(16) ushort_t smem[2 * 128 * RS];
  ushort_t* As = smem;
  ushort_t* Bs = smem + 128 * RS;
  const int t = threadIdx.x;
  const int m0 = blockIdx.x * 128, n0 = blockIdx.y * 128;
  const int lane = t & 63, wv = t >> 6;
  const int l16 = lane & 15, quad = lane >> 4;

  f32x4 acc[2][8];
#pragma unroll
  for (int b = 0; b < 2; ++b)
#pragma unroll
    for (int n = 0; n < 8; ++n) acc[b][n] = (f32x4){0.f, 0.f, 0.f, 0.f};

  for (int k0 = 0; k0 < KDIM; k0 += 64) {
    __syncthreads();
    {
      const int r = t >> 3, seg = t & 7;
#pragma unroll
      for (int p = 0; p < 4; ++p) {
        int m = m0 + r + p * 32;
        int ms = (m < NN) ? m : NN - 1;
        *(uint4*)(As + (r + p * 32) * RS + seg * 8) =
            *(const uint4*)(Ab + (size_t)ms * KDIM + k0 + seg * 8);
        *(uint4*)(Bs + (r + p * 32) * RS + seg * 8) =
            *(const uint4*)(BW + (size_t)(n0 + r + p * 32) * KDIM + k0 + seg * 8);
      }
    }
    __syncthreads();
#pragma unroll
    for (int kk = 0; kk < 2; ++kk) {
      bf16x8 a[2];
#pragma unroll
      for (int b = 0; b < 2; ++b)
        a[b] = *(const bf16x8*)(As + (wv * 32 + b * 16 + l16) * RS + kk * 32 + quad * 8);
#pragma unroll
      for (int n = 0; n < 8; ++n) {
        bf16x8 bb = *(const bf16x8*)(Bs + (n * 16 + l16) * RS + kk * 32 + quad * 8);
        acc[0][n] = __builtin_amdgcn_mfma_f32_16x16x32_bf16(a[0], bb, acc[0][n], 0, 0, 0);
        acc[1][n] = __builtin_amdgcn_mfma_f32_16x16x32_bf16(a[1], bb, acc[1][n], 0, 0, 0);
      }
    }
  }

  // ---- epilogue: per-wave LDS transpose -> coalesced stores ----
  __syncthreads();   // retire staging reads before smem reuse
  ushort_t* band = smem + wv * 32 * EPS;
  const float* bp = (n0 < nhalf) ? bl : br;
  const int nb = (n0 < nhalf) ? n0 : n0 - nhalf;
#pragma unroll
  for (int n = 0; n < 8; ++n) {
    const float bv = bp[nb + n * 16 + l16];
#pragma unroll
    for (int b = 0; b < 2; ++b)
#pragma unroll
      for (int r = 0; r < 4; ++r)
        band[(b * 16 + quad * 4 + r) * EPS + n * 16 + l16] = bf16r(acc[b][n][r] + bv);
  }
  const int rl   = lane >> 4;   // row within 4-row group
  const int cseg = lane & 15;   // 16B segment within row
#pragma unroll
  for (int g = 0; g < 8; ++g) {
    const int row_local = g * 4 + rl;
    const int row = m0 + wv * 32 + row_local;
    uint4 vx = *(const uint4*)(band + row_local * EPS + cseg * 8);
    if (row < NN)
      *(uint4*)(C + (size_t)row * nstride + n0 + cseg * 8) = vx;
  }
}

// ---------------- GATv2 layer ----------------
// One wave per dst node; each block owns 4 CONSECUTIVE slots (16 adjacent
// nodes, same graph -- preserves the R2 L2-residency, unlike R7's strided
// version). attn hoisted across the 4 nodes. XCD-contiguous ranges.
// No-max softmax; scalar start/deg (s_load cp[e]); depth-2 load pipeline;
// log2e folded into attn (exp2); gate dot in epilogue.

template<int N32> struct UV;
template<> struct UV<2> { typedef uint2 T; };
template<> struct UV<4> { typedef uint4 T; };

#define GAT_SLOTS 1563                       // slots per XCD (ceil(12500/8))
#define GAT_BLKX  ((GAT_SLOTS + 3) / 4)      // 391 blocks per XCD
#define GAT_GRID  (GAT_BLKX * 8)             // 3128 blocks

template<int D, int STRIDE, bool OUTBF, bool GATE>
__global__ __launch_bounds__(256)
void gat_layer(const ushort_t* __restrict__ fsb, const ushort_t* __restrict__ fdb,
               const float* __restrict__ attn,
               const int* __restrict__ rowstart, const int* __restrict__ deg,
               const int* __restrict__ csr_src,
               float4* __restrict__ out4, ushort_t* __restrict__ outb,
               const float* __restrict__ gw, float* __restrict__ gate) {
  constexpr int DPL = D / 16;   // dims per lane (8 or 4)
  constexpr int NU  = DPL / 2;  // float2s per lane (4 or 2)
  constexpr int NV4 = DPL / 4;  // float4s per lane for fp32 output
  constexpr int D4  = D / 4;
  typedef typename UV<NU>::T LT;

  const int b    = blockIdx.x;
  const int xcd  = b & 7;
  const int bi   = b >> 3;
  const int lane = threadIdx.x & 63;
  const int wvid = threadIdx.x >> 6;
  const int h    = lane >> 4;
  const int g16  = lane & 15;
  const int foff = h * D + g16 * DPL;

  // hoisted across the 4 nodes
  f32x2 at2[NU];
  {
    const float* ap = attn + foff;
#pragma unroll
    for (int j = 0; j < NU; ++j) {
      at2[j].x = ap[2 * j] * 1.44269504f;       // fold log2(e)
      at2[j].y = ap[2 * j + 1] * 1.44269504f;
    }
  }

  for (int jj = 0; jj < 4; ++jj) {
    const int si = bi * 4 + jj;
    if (si >= GAT_SLOTS) break;
    const int slot = xcd * GAT_SLOTS + si;
    if (slot >= NN / 4) break;
    const int v = (slot << 2) + wvid;

    f32x2 fd2[NU];
    {
      LT raw = *reinterpret_cast<const LT*>(fdb + (size_t)v * STRIDE + foff);
      const uint_t* rw = reinterpret_cast<const uint_t*>(&raw);
#pragma unroll
      for (int j = 0; j < NU; ++j) fd2[j] = up2v(rw[j]);
    }
    const int start = __builtin_amdgcn_readfirstlane(rowstart[v]);
    const int n     = __builtin_amdgcn_readfirstlane(deg[v]);
    const int* cp   = csr_src + start;

    float s = 0.f;
    f32x2 acc2[NU];
#pragma unroll
    for (int j = 0; j < NU; ++j) acc2[j] = (f32x2){0.f, 0.f};

    if (n > 0) {
      // depth-2 pipeline: two fs-row loads in flight
      LT r0 = *reinterpret_cast<const LT*>(fsb + (size_t)cp[0] * STRIDE + foff);
      LT r1 = r0;
      if (n > 1)
        r1 = *reinterpret_cast<const LT*>(fsb + (size_t)cp[1] * STRIDE + foff);
      for (int e = 0; e < n; ++e) {
        const LT cur = r0;
        r0 = r1;
        if (e + 2 < n)
          r1 = *reinterpret_cast<const LT*>(fsb + (size_t)cp[e + 2] * STRIDE + foff);
        const uint_t* rw = reinterpret_cast<const uint_t*>(&cur);
        f32x2 f0[NU];
#pragma unroll
        for (int j = 0; j < NU; ++j) f0[j] = up2v(rw[j]);
        f32x2 p2 = (f32x2){0.f, 0.f};
#pragma unroll
        for (int j = 0; j < NU; ++j) {
          f32x2 t = f0[j] + fd2[j];
          f32x2 l = __builtin_elementwise_max(t, t * 0.2f);   // leaky_relu 0.2
          p2 = __builtin_elementwise_fma(l, at2[j], p2);
        }
        float p = p2.x + p2.y;
        p += __shfl_xor(p, 1);
        p += __shfl_xor(p, 2);
        p += __shfl_xor(p, 4);
        p += __shfl_xor(p, 8);
        const float w = exp2f(p);   // attn pre-scaled by log2e
        s += w;
        const f32x2 wv2 = {w, w};
#pragma unroll
        for (int j = 0; j < NU; ++j)
          acc2[j] = __builtin_elementwise_fma(wv2, f0[j], acc2[j]);
      }
    }

    const float rs = (n > 0) ? (1.0f / s) : 0.f;
    float acc[DPL];
#pragma unroll
    for (int j = 0; j < NU; ++j) {
      acc[2 * j]     = acc2[j].x * rs;
      acc[2 * j + 1] = acc2[j].y * rs;
    }
#pragma unroll
    for (int i = 0; i < DPL; ++i) {
      acc[i] = fmaxf(acc[i], __shfl_xor(acc[i], 16));   // max over heads
      acc[i] = fmaxf(acc[i], __shfl_xor(acc[i], 32));
    }
    if constexpr (GATE) {
      // gate[v] = h2[v].gw ; gw loaded here (short live range). Each dim is
      // held by 4 lanes -> full-wave sum * 0.25.
      const float* gp = gw + g16 * DPL;
      float g = 0.f;
#pragma unroll
      for (int i = 0; i < DPL; ++i) g = fmaf(acc[i], gp[i], g);
      g += __shfl_xor(g, 1);  g += __shfl_xor(g, 2);  g += __shfl_xor(g, 4);
      g += __shfl_xor(g, 8);  g += __shfl_xor(g, 16); g += __shfl_xor(g, 32);
      if (lane == 0) gate[v] = g * 0.25f;
    }
    if (h == 0) {
      if constexpr (OUTBF) {
        ushort4 o;
        o.x = bf16r(acc[0]); o.y = bf16r(acc[1]); o.z = bf16r(acc[2]); o.w = bf16r(acc[3]);
        *reinterpret_cast<ushort4*>(outb + (size_t)v * D + g16 * 4) = o;
      } else {
#pragma unroll
        for (int i = 0; i < NV4; ++i)
          out4[(size_t)v * D4 + g16 * NV4 + i] =
              make_float4(acc[4 * i], acc[4 * i + 1], acc[4 * i + 2], acc[4 * i + 3]);
      }
    }
  }
}

// ---------------- pooling: one block per graph; gate precomputed by gat128 ----------------

__global__ __launch_bounds__(1024)
void pool_fused(const float* __restrict__ gate, const float* __restrict__ h2,
                float* __restrict__ out) {
  const int g = blockIdx.x, t = threadIdx.x;
  const int lane = t & 63, w = t >> 6;
  __shared__ float a_s[NPG];
  __shared__ float red[16];
  __shared__ float fin;
  __shared__ float part[8][128];

  float gv = (t < NPG) ? gate[g * NPG + t] : -__builtin_inff();
  float m = gv;
  m = fmaxf(m, __shfl_xor(m, 1));  m = fmaxf(m, __shfl_xor(m, 2));
  m = fmaxf(m, __shfl_xor(m, 4));  m = fmaxf(m, __shfl_xor(m, 8));
  m = fmaxf(m, __shfl_xor(m, 16)); m = fmaxf(m, __shfl_xor(m, 32));
  if (lane == 0) red[w] = m;
  __syncthreads();
  if (t == 0) {
    float r = red[0];
#pragma unroll
    for (int j = 1; j < 16; ++j) r = fmaxf(r, red[j]);
    fin = r;
  }
  __syncthreads();
  const float gm = fin;

  float ex = (t < NPG) ? __expf(gv - gm) : 0.f;
  float s = ex;
  s += __shfl_xor(s, 1);  s += __shfl_xor(s, 2);  s += __shfl_xor(s, 4);
  s += __shfl_xor(s, 8);  s += __shfl_xor(s, 16); s += __shfl_xor(s, 32);
  if (lane == 0) red[w] = s;
  __syncthreads();
  if (t == 0) {
    float r = 0.f;
#pragma unroll
    for (int j = 0; j < 16; ++j) r += red[j];
    fin = 1.0f / r;
  }
  __syncthreads();
  if (t < NPG) a_s[t] = ex * fin;
  __syncthreads();

  const int d = t & 127;   // dim
  const int c = t >> 7;    // chunk 0..7
  float acc = 0.f;
  for (int i = c; i < NPG; i += 8)
    acc = fmaf(a_s[i], h2[(size_t)(g * NPG + i) * 128 + d], acc);
  part[c][d] = acc;
  __syncthreads();
  if (c == 0) {
    float r = acc;
#pragma unroll
    for (int j = 1; j < 8; ++j) r += part[j][d];
    out[g * 128 + d] = r;
  }
}

// ---------------- launch ----------------

extern "C" void kernel_launch(void* const* d_in, const int* in_sizes, int n_in,
                              void* d_out, int out_size, void* d_ws, size_t ws_size,
                              hipStream_t stream) {
  const float* x        = (const float*)d_in[0];
  const int*   edge_src = (const int*)d_in[1];
  const int*   edge_dst = (const int*)d_in[2];
  // d_in[3] = node_graph (graph id = v / 1000 by construction; unused)
  const float* Wl1   = (const float*)d_in[4];
  const float* bl1   = (const float*)d_in[5];
  const float* Wr1   = (const float*)d_in[6];
  const float* br1   = (const float*)d_in[7];
  const float* attn1 = (const float*)d_in[8];
  const float* Wl2   = (const float*)d_in[9];
  const float* bl2   = (const float*)d_in[10];
  const float* Wr2   = (const float*)d_in[11];
  const float* br2   = (const float*)d_in[12];
  const float* attn2 = (const float*)d_in[13];
  const float* gate_w = (const float*)d_in[14];
  // d_in[15] = gate_b (cancels in softmax)
  float* out = (float*)d_out;

  // workspace: fsd1 [NN x 512 bf16] unions with fsd2 [NN x 1024 bf16]
  ushort_t* fsd1 = (ushort_t*)d_ws;                       // NN*512 bf16
  ushort_t* fsd2 = fsd1;                                  // NN*1024 bf16 (union)
  ushort_t* h1b  = fsd2 + (size_t)NN * 1024;              // NN*64 bf16
  float* h2      = (float*)(h1b + (size_t)NN * 64);       // NN*128 f32
  float* gate    = h2 + (size_t)NN * 128;                 // NN f32
  ushort_t* BW1  = (ushort_t*)(gate + NN);                // 512*128 bf16
  ushort_t* BW2  = BW1 + 512 * 128;                       // 1024*64 bf16
  ushort_t* xb   = BW2 + 1024 * 64;                       // NN*128 bf16
  int* counts   = (int*)(xb + (size_t)NN * 128);          // NN
  int* rowstart = counts + NN;
  int* cursor   = rowstart + NN;
  int* csr_src  = cursor + NN;                            // EE
  int* bsum     = csr_src + EE;                           // 256

  hipMemsetAsync(counts, 0, NN * sizeof(int), stream);

  const int nbN = (NN + 255) / 256;   // 196
  const int MB  = (NN + 127) / 128;   // 391

  prep_count<<<NB_E + NB_W + NB_X, 256, 0, stream>>>(
      edge_dst, counts, Wl1, Wr1, Wl2, Wr2, BW1, BW2, x, xb);
  scan_block<<<nbN, 256, 0, stream>>>(counts, rowstart, bsum, NN);
  scan_add<<<nbN, 256, 0, stream>>>(bsum, rowstart, cursor, NN);
  scatter_edges<<<NB_E, 256, 0, stream>>>(edge_src, edge_dst, rowstart, cursor, csr_src);

  gemm_mfma<128><<<dim3(MB, 4), 256, 0, stream>>>(
      xb, BW1, bl1, br1, 256, fsd1, 512);
  gat_layer<64, 512, true, false><<<GAT_GRID, 256, 0, stream>>>(
      fsd1, fsd1 + 256, attn1, rowstart, counts, csr_src,
      nullptr, h1b, nullptr, nullptr);
  gemm_mfma<64><<<dim3(MB, 8), 256, 0, stream>>>(
      h1b, BW2, bl2, br2, 512, fsd2, 1024);
  gat_layer<128, 1024, false, true><<<GAT_GRID, 256, 0, stream>>>(
      fsd2, fsd2 + 512, attn2, rowstart, counts, csr_src,
      (float4*)h2, nullptr, gate_w, gate);

  pool_fused<<<GG, 1024, 0, stream>>>(gate, h2, out);
}

// Round 15
// 336.817 us; speedup vs baseline: 1.0591x; 1.0591x over previous
//
#include <hip/hip_runtime.h>
#include <hip/hip_bf16.h>

// GATv2 x2 + GlobalAttentionPooling for batched graphs.
// N=50000 nodes, E=500000 edges, G=50 graphs (1000 nodes each, edges in-graph).
// Layer1: IN=128 -> H=4 x D=64 (head-max -> 64). Layer2: 64 -> 4 x 128 (head-max -> 128).
// Pool: softmax(gate) per graph, weighted sum -> [50,128].
//
// R1: pooling atomics -> block-per-graph LDS. 1127->570us.
// R2: gat bf16 + XCD-contiguous swizzle (FETCH 444->54MB). ->488us.
// R3: fp32-VALU GEMMs -> bf16 MFMA (LDS-staged). ->422us.
// R4-R8: no-max softmax + packed f32x2 kept; strided slots / unroll / bcast BAD.
// R9: 1-deep load pipeline + scalar cp[e] + epilogue gate: gat128 88->69. ->377us.
// R10: FAILED 2-wave edge split. R11: depth-2 pipeline. ->370us.
// R12: FAILED LDS-free GEMM; exposed 2.7x C-store write amplification.
// R13: coalesced LDS-transpose GEMM epilogue. ->339us (best).
// R14: FAILED 4-slot gat loop (waves /4, FETCH 55->71MB, occ 43%). Bundled
//   infra (fused scan, x-precast) was fine.
// R15: gat reverted to R13 exact (1 slot/block, 12504 blocks); kept R14 infra:
//   scan_bsum folded into scan_add (-1 dispatch), x precast to bf16 (gemm1
//   A-fetch halved, no cvt in staging), bf16-only GEMM template.

#define NN 50000
#define EE 500000
#define GG 50
#define NPG 1000
#define HH 4
#define NB_E ((EE + 255) / 256)        // 1954 edge-count blocks
#define NB_W 512                       // weight prep blocks
#define NB_X ((NN * 128) / (256 * 4))  // 6250 x-cast blocks (float4 each)

typedef unsigned short ushort_t;
typedef unsigned int uint_t;
typedef __attribute__((ext_vector_type(8))) short bf16x8;
typedef __attribute__((ext_vector_type(4))) float f32x4;
typedef __attribute__((ext_vector_type(2))) float f32x2;

__device__ __forceinline__ ushort_t bf16r(float f) {
  __hip_bfloat16 h = __float2bfloat16(f);
  return *reinterpret_cast<ushort_t*>(&h);
}

__device__ __forceinline__ f32x2 up2v(uint_t u) {
  f32x2 r;
  r.x = __uint_as_float(u << 16);
  r.y = __uint_as_float(u & 0xffff0000u);
  return r;
}

// ---------------- fused weight-prep + edge count + x cast ----------------

__global__ void prep_count(const int* __restrict__ dst, int* __restrict__ counts,
                           const float* __restrict__ Wl1, const float* __restrict__ Wr1,
                           const float* __restrict__ Wl2, const float* __restrict__ Wr2,
                           ushort_t* __restrict__ BW1, ushort_t* __restrict__ BW2,
                           const float* __restrict__ x, ushort_t* __restrict__ xb) {
  const int b = blockIdx.x;
  if (b < NB_E) {
    int i = b * 256 + threadIdx.x;
    if (i < EE) atomicAdd(&counts[dst[i]], 1);
  } else if (b < NB_E + NB_W) {
    int i = (b - NB_E) * 256 + threadIdx.x;   // 0..131071
    if (i < 512 * 128) {                      // BW1: [n<512][k<128], W1 [128][256]
      int n = i >> 7, k = i & 127;
      const float* W = (n < 256) ? Wl1 : Wr1;
      BW1[i] = bf16r(W[(size_t)k * 256 + (n & 255)]);
    } else {                                  // BW2: [n<1024][k<64], W2 [64][512]
      int j = i - 512 * 128;
      int n = j >> 6, k = j & 63;
      const float* W = (n < 512) ? Wl2 : Wr2;
      BW2[j] = bf16r(W[(size_t)k * 512 + (n & 511)]);
    }
  } else {
    // x -> bf16, 4 floats per thread
    size_t i = (size_t)(b - NB_E - NB_W) * 256 + threadIdx.x;
    float4 v = *(const float4*)(x + i * 4);
    uint2 pk;
    pk.x = (uint_t)bf16r(v.x) | ((uint_t)bf16r(v.y) << 16);
    pk.y = (uint_t)bf16r(v.z) | ((uint_t)bf16r(v.w) << 16);
    *(uint2*)(xb + i * 4) = pk;
  }
}

// ---------------- CSR scan (2 kernels) ----------------

__global__ void scan_block(const int* __restrict__ in, int* __restrict__ out,
                           int* __restrict__ bsum, int n) {
  __shared__ int tmp[256];
  int t = threadIdx.x;
  int i = blockIdx.x * 256 + t;
  int v = (i < n) ? in[i] : 0;
  tmp[t] = v;
  __syncthreads();
  for (int off = 1; off < 256; off <<= 1) {
    int a = (t >= off) ? tmp[t - off] : 0;
    __syncthreads();
    tmp[t] += a;
    __syncthreads();
  }
  if (i < n) out[i] = tmp[t] - v;
  if (t == 255) bsum[blockIdx.x] = tmp[t];
}

// adds prefix of bsum[0..blockIdx.x) to out (computed in-block); zeros cursor.
__global__ void scan_add(const int* __restrict__ bsum, int* __restrict__ out,
                         int* __restrict__ cursor, int n) {
  __shared__ int sred[4];
  const int t = threadIdx.x;
  const int b = blockIdx.x;
  int v = (t < b) ? bsum[t] : 0;   // nb=196 <= 256, covered
  v += __shfl_xor(v, 1);  v += __shfl_xor(v, 2);  v += __shfl_xor(v, 4);
  v += __shfl_xor(v, 8);  v += __shfl_xor(v, 16); v += __shfl_xor(v, 32);
  if ((t & 63) == 0) sred[t >> 6] = v;
  __syncthreads();
  const int base = sred[0] + sred[1] + sred[2] + sred[3];
  int i = b * 256 + t;
  if (i < n) {
    out[i] += base;
    cursor[i] = 0;
  }
}

__global__ void scatter_edges(const int* __restrict__ src, const int* __restrict__ dst,
                              const int* __restrict__ rowstart, int* __restrict__ cursor,
                              int* __restrict__ csr_src) {
  int i = blockIdx.x * 256 + threadIdx.x;
  if (i < EE) {
    int d = dst[i];
    int p = atomicAdd(&cursor[d], 1);
    csr_src[rowstart[d] + p] = src[i];
  }
}

// ---------------- bf16 MFMA GEMM: C[m][n] = A[m][:] . BW[n][:] + bias ----------------
// K-loop: LDS-staged (coalesced), 128x128 tile, 4 waves x (2x8) 16x16x32 mfma.
// Epilogue: wave-private LDS transpose band -> coalesced uint4 stores (R13).

template<int KDIM>
__global__ __launch_bounds__(256)
void gemm_mfma(const ushort_t* __restrict__ Ab, const ushort_t* __restrict__ BW,
               const float* __restrict__ bl, const float* __restrict__ br, int nhalf,
               ushort_t* __restrict__ C, int nstride) {
  constexpr int RS  = 72;    // staging row stride (bf16)
  constexpr int EPS = 132;   // epilogue row stride (bf16); 4*32*132 <= 2*128*72
  __shared__ __align__(16) ushort_t smem[2 * 128 * RS];
  ushort_t* As = smem;
  ushort_t* Bs = smem + 128 * RS;
  const int t = threadIdx.x;
  const int m0 = blockIdx.x * 128, n0 = blockIdx.y * 128;
  const int lane = t & 63, wv = t >> 6;
  const int l16 = lane & 15, quad = lane >> 4;

  f32x4 acc[2][8];
#pragma unroll
  for (int b = 0; b < 2; ++b)
#pragma unroll
    for (int n = 0; n < 8; ++n) acc[b][n] = (f32x4){0.f, 0.f, 0.f, 0.f};

  for (int k0 = 0; k0 < KDIM; k0 += 64) {
    __syncthreads();
    {
      const int r = t >> 3, seg = t & 7;
#pragma unroll
      for (int p = 0; p < 4; ++p) {
        int m = m0 + r + p * 32;
        int ms = (m < NN) ? m : NN - 1;
        *(uint4*)(As + (r + p * 32) * RS + seg * 8) =
            *(const uint4*)(Ab + (size_t)ms * KDIM + k0 + seg * 8);
        *(uint4*)(Bs + (r + p * 32) * RS + seg * 8) =
            *(const uint4*)(BW + (size_t)(n0 + r + p * 32) * KDIM + k0 + seg * 8);
      }
    }
    __syncthreads();
#pragma unroll
    for (int kk = 0; kk < 2; ++kk) {
      bf16x8 a[2];
#pragma unroll
      for (int b = 0; b < 2; ++b)
        a[b] = *(const bf16x8*)(As + (wv * 32 + b * 16 + l16) * RS + kk * 32 + quad * 8);
#pragma unroll
      for (int n = 0; n < 8; ++n) {
        bf16x8 bb = *(const bf16x8*)(Bs + (n * 16 + l16) * RS + kk * 32 + quad * 8);
        acc[0][n] = __builtin_amdgcn_mfma_f32_16x16x32_bf16(a[0], bb, acc[0][n], 0, 0, 0);
        acc[1][n] = __builtin_amdgcn_mfma_f32_16x16x32_bf16(a[1], bb, acc[1][n], 0, 0, 0);
      }
    }
  }

  // ---- epilogue: per-wave LDS transpose -> coalesced stores ----
  __syncthreads();   // retire staging reads before smem reuse
  ushort_t* band = smem + wv * 32 * EPS;
  const float* bp = (n0 < nhalf) ? bl : br;
  const int nb = (n0 < nhalf) ? n0 : n0 - nhalf;
#pragma unroll
  for (int n = 0; n < 8; ++n) {
    const float bv = bp[nb + n * 16 + l16];
#pragma unroll
    for (int b = 0; b < 2; ++b)
#pragma unroll
      for (int r = 0; r < 4; ++r)
        band[(b * 16 + quad * 4 + r) * EPS + n * 16 + l16] = bf16r(acc[b][n][r] + bv);
  }
  const int rl   = lane >> 4;   // row within 4-row group
  const int cseg = lane & 15;   // 16B segment within row
#pragma unroll
  for (int g = 0; g < 8; ++g) {
    const int row_local = g * 4 + rl;
    const int row = m0 + wv * 32 + row_local;
    uint4 vx = *(const uint4*)(band + row_local * EPS + cseg * 8);
    if (row < NN)
      *(uint4*)(C + (size_t)row * nstride + n0 + cseg * 8) = vx;
  }
}

// ---------------- GATv2 layer (R13 exact structure) ----------------
// One wave per dst node, ONE slot (4 nodes) per block, XCD-contiguous slot
// ranges -- max TLP (50016 waves) + per-graph L2 residency. lane = h*16+g16.
// No-max softmax; scalar start/deg (s_load cp[e]); depth-2 load pipeline;
// log2e folded into attn (exp2); gate dot in epilogue.

template<int N32> struct UV;
template<> struct UV<2> { typedef uint2 T; };
template<> struct UV<4> { typedef uint4 T; };

#define GAT_SLOTS ((NN / 4 + 7) / 8)        // 1563 slots per XCD
#define GAT_GRID  (GAT_SLOTS * 8)           // 12504 blocks

template<int D, int STRIDE, bool OUTBF, bool GATE>
__global__ __launch_bounds__(256)
void gat_layer(const ushort_t* __restrict__ fsb, const ushort_t* __restrict__ fdb,
               const float* __restrict__ attn,
               const int* __restrict__ rowstart, const int* __restrict__ deg,
               const int* __restrict__ csr_src,
               float4* __restrict__ out4, ushort_t* __restrict__ outb,
               const float* __restrict__ gw, float* __restrict__ gate) {
  constexpr int DPL = D / 16;   // dims per lane (8 or 4)
  constexpr int NU  = DPL / 2;  // float2s per lane (4 or 2)
  constexpr int NV4 = DPL / 4;  // float4s per lane for fp32 output
  constexpr int D4  = D / 4;
  typedef typename UV<NU>::T LT;

  const int b    = blockIdx.x;
  const int slot = (b & 7) * GAT_SLOTS + (b >> 3);
  if (slot >= NN / 4) return;
  const int lane = threadIdx.x & 63;
  const int wvid = threadIdx.x >> 6;
  const int v    = (slot << 2) + wvid;
  const int h    = lane >> 4;
  const int g16  = lane & 15;
  const int foff = h * D + g16 * DPL;

  f32x2 at2[NU], fd2[NU];
  {
    const float* ap = attn + foff;
#pragma unroll
    for (int j = 0; j < NU; ++j) {
      at2[j].x = ap[2 * j] * 1.44269504f;       // fold log2(e): exp(p)=exp2(p')
      at2[j].y = ap[2 * j + 1] * 1.44269504f;
    }
    LT raw = *reinterpret_cast<const LT*>(fdb + (size_t)v * STRIDE + foff);
    const uint_t* rw = reinterpret_cast<const uint_t*>(&raw);
#pragma unroll
    for (int j = 0; j < NU; ++j) fd2[j] = up2v(rw[j]);
  }
  // wave-uniform scalars -> SGPRs; cp[e] becomes an s_load
  const int start = __builtin_amdgcn_readfirstlane(rowstart[v]);
  const int n     = __builtin_amdgcn_readfirstlane(deg[v]);
  const int* cp   = csr_src + start;

  float s = 0.f;
  f32x2 acc2[NU];
#pragma unroll
  for (int j = 0; j < NU; ++j) acc2[j] = (f32x2){0.f, 0.f};

  if (n > 0) {
    // depth-2 pipeline: r0 = edge e's row, r1 = edge e+1's row (in flight)
    LT r0 = *reinterpret_cast<const LT*>(fsb + (size_t)cp[0] * STRIDE + foff);
    LT r1 = r0;
    if (n > 1)   // uniform branch
      r1 = *reinterpret_cast<const LT*>(fsb + (size_t)cp[1] * STRIDE + foff);
    for (int e = 0; e < n; ++e) {
      const LT cur = r0;
      r0 = r1;
      if (e + 2 < n)   // uniform branch
        r1 = *reinterpret_cast<const LT*>(fsb + (size_t)cp[e + 2] * STRIDE + foff);
      const uint_t* rw = reinterpret_cast<const uint_t*>(&cur);
      f32x2 f0[NU];
#pragma unroll
      for (int j = 0; j < NU; ++j) f0[j] = up2v(rw[j]);
      f32x2 p2 = (f32x2){0.f, 0.f};
#pragma unroll
      for (int j = 0; j < NU; ++j) {
        f32x2 t = f0[j] + fd2[j];
        f32x2 l = __builtin_elementwise_max(t, t * 0.2f);   // leaky_relu 0.2
        p2 = __builtin_elementwise_fma(l, at2[j], p2);
      }
      float p = p2.x + p2.y;
      p += __shfl_xor(p, 1);
      p += __shfl_xor(p, 2);
      p += __shfl_xor(p, 4);
      p += __shfl_xor(p, 8);
      const float w = exp2f(p);   // attn pre-scaled by log2e
      s += w;
      const f32x2 wv2 = {w, w};
#pragma unroll
      for (int j = 0; j < NU; ++j)
        acc2[j] = __builtin_elementwise_fma(wv2, f0[j], acc2[j]);
    }
  }

  const float rs = (n > 0) ? (1.0f / s) : 0.f;
  float acc[DPL];
#pragma unroll
  for (int j = 0; j < NU; ++j) {
    acc[2 * j]     = acc2[j].x * rs;
    acc[2 * j + 1] = acc2[j].y * rs;
  }
#pragma unroll
  for (int i = 0; i < DPL; ++i) {
    acc[i] = fmaxf(acc[i], __shfl_xor(acc[i], 16));   // max over heads
    acc[i] = fmaxf(acc[i], __shfl_xor(acc[i], 32));
  }
  if constexpr (GATE) {
    // gate[v] = h2[v].gw ; gw loaded here (short live range). Each dim is
    // held by 4 lanes -> full-wave sum * 0.25.
    const float* gp = gw + g16 * DPL;
    float g = 0.f;
#pragma unroll
    for (int i = 0; i < DPL; ++i) g = fmaf(acc[i], gp[i], g);
    g += __shfl_xor(g, 1);  g += __shfl_xor(g, 2);  g += __shfl_xor(g, 4);
    g += __shfl_xor(g, 8);  g += __shfl_xor(g, 16); g += __shfl_xor(g, 32);
    if (lane == 0) gate[v] = g * 0.25f;
  }
  if (h == 0) {
    if constexpr (OUTBF) {
      ushort4 o;
      o.x = bf16r(acc[0]); o.y = bf16r(acc[1]); o.z = bf16r(acc[2]); o.w = bf16r(acc[3]);
      *reinterpret_cast<ushort4*>(outb + (size_t)v * D + g16 * 4) = o;
    } else {
#pragma unroll
      for (int i = 0; i < NV4; ++i)
        out4[(size_t)v * D4 + g16 * NV4 + i] =
            make_float4(acc[4 * i], acc[4 * i + 1], acc[4 * i + 2], acc[4 * i + 3]);
    }
  }
}

// ---------------- pooling: one block per graph; gate precomputed by gat128 ----------------

__global__ __launch_bounds__(1024)
void pool_fused(const float* __restrict__ gate, const float* __restrict__ h2,
                float* __restrict__ out) {
  const int g = blockIdx.x, t = threadIdx.x;
  const int lane = t & 63, w = t >> 6;
  __shared__ float a_s[NPG];
  __shared__ float red[16];
  __shared__ float fin;
  __shared__ float part[8][128];

  float gv = (t < NPG) ? gate[g * NPG + t] : -__builtin_inff();
  float m = gv;
  m = fmaxf(m, __shfl_xor(m, 1));  m = fmaxf(m, __shfl_xor(m, 2));
  m = fmaxf(m, __shfl_xor(m, 4));  m = fmaxf(m, __shfl_xor(m, 8));
  m = fmaxf(m, __shfl_xor(m, 16)); m = fmaxf(m, __shfl_xor(m, 32));
  if (lane == 0) red[w] = m;
  __syncthreads();
  if (t == 0) {
    float r = red[0];
#pragma unroll
    for (int j = 1; j < 16; ++j) r = fmaxf(r, red[j]);
    fin = r;
  }
  __syncthreads();
  const float gm = fin;

  float ex = (t < NPG) ? __expf(gv - gm) : 0.f;
  float s = ex;
  s += __shfl_xor(s, 1);  s += __shfl_xor(s, 2);  s += __shfl_xor(s, 4);
  s += __shfl_xor(s, 8);  s += __shfl_xor(s, 16); s += __shfl_xor(s, 32);
  if (lane == 0) red[w] = s;
  __syncthreads();
  if (t == 0) {
    float r = 0.f;
#pragma unroll
    for (int j = 0; j < 16; ++j) r += red[j];
    fin = 1.0f / r;
  }
  __syncthreads();
  if (t < NPG) a_s[t] = ex * fin;
  __syncthreads();

  const int d = t & 127;   // dim
  const int c = t >> 7;    // chunk 0..7
  float acc = 0.f;
  for (int i = c; i < NPG; i += 8)
    acc = fmaf(a_s[i], h2[(size_t)(g * NPG + i) * 128 + d], acc);
  part[c][d] = acc;
  __syncthreads();
  if (c == 0) {
    float r = acc;
#pragma unroll
    for (int j = 1; j < 8; ++j) r += part[j][d];
    out[g * 128 + d] = r;
  }
}

// ---------------- launch ----------------

extern "C" void kernel_launch(void* const* d_in, const int* in_sizes, int n_in,
                              void* d_out, int out_size, void* d_ws, size_t ws_size,
                              hipStream_t stream) {
  const float* x        = (const float*)d_in[0];
  const int*   edge_src = (const int*)d_in[1];
  const int*   edge_dst = (const int*)d_in[2];
  // d_in[3] = node_graph (graph id = v / 1000 by construction; unused)
  const float* Wl1   = (const float*)d_in[4];
  const float* bl1   = (const float*)d_in[5];
  const float* Wr1   = (const float*)d_in[6];
  const float* br1   = (const float*)d_in[7];
  const float* attn1 = (const float*)d_in[8];
  const float* Wl2   = (const float*)d_in[9];
  const float* bl2   = (const float*)d_in[10];
  const float* Wr2   = (const float*)d_in[11];
  const float* br2   = (const float*)d_in[12];
  const float* attn2 = (const float*)d_in[13];
  const float* gate_w = (const float*)d_in[14];
  // d_in[15] = gate_b (cancels in softmax)
  float* out = (float*)d_out;

  // workspace: fsd1 [NN x 512 bf16] unions with fsd2 [NN x 1024 bf16]
  ushort_t* fsd1 = (ushort_t*)d_ws;                       // NN*512 bf16
  ushort_t* fsd2 = fsd1;                                  // NN*1024 bf16 (union)
  ushort_t* h1b  = fsd2 + (size_t)NN * 1024;              // NN*64 bf16
  float* h2      = (float*)(h1b + (size_t)NN * 64);       // NN*128 f32
  float* gate    = h2 + (size_t)NN * 128;                 // NN f32
  ushort_t* BW1  = (ushort_t*)(gate + NN);                // 512*128 bf16
  ushort_t* BW2  = BW1 + 512 * 128;                       // 1024*64 bf16
  ushort_t* xb   = BW2 + 1024 * 64;                       // NN*128 bf16
  int* counts   = (int*)(xb + (size_t)NN * 128);          // NN
  int* rowstart = counts + NN;
  int* cursor   = rowstart + NN;
  int* csr_src  = cursor + NN;                            // EE
  int* bsum     = csr_src + EE;                           // 256

  hipMemsetAsync(counts, 0, NN * sizeof(int), stream);

  const int nbN = (NN + 255) / 256;   // 196
  const int MB  = (NN + 127) / 128;   // 391

  prep_count<<<NB_E + NB_W + NB_X, 256, 0, stream>>>(
      edge_dst, counts, Wl1, Wr1, Wl2, Wr2, BW1, BW2, x, xb);
  scan_block<<<nbN, 256, 0, stream>>>(counts, rowstart, bsum, NN);
  scan_add<<<nbN, 256, 0, stream>>>(bsum, rowstart, cursor, NN);
  scatter_edges<<<NB_E, 256, 0, stream>>>(edge_src, edge_dst, rowstart, cursor, csr_src);

  gemm_mfma<128><<<dim3(MB, 4), 256, 0, stream>>>(
      xb, BW1, bl1, br1, 256, fsd1, 512);
  gat_layer<64, 512, true, false><<<GAT_GRID, 256, 0, stream>>>(
      fsd1, fsd1 + 256, attn1, rowstart, counts, csr_src,
      nullptr, h1b, nullptr, nullptr);
  gemm_mfma<64><<<dim3(MB, 8), 256, 0, stream>>>(
      h1b, BW2, bl2, br2, 512, fsd2, 1024);
  gat_layer<128, 1024, false, true><<<GAT_GRID, 256, 0, stream>>>(
      fsd2, fsd2 + 512, attn2, rowstart, counts, csr_src,
      (float4*)h2, nullptr, gate_w, gate);

  pool_fused<<<GG, 1024, 0, stream>>>(gate, h2, out);
}